// Round 6
// baseline (359.533 us; speedup 1.0000x reference)
//
#include <hip/hip_runtime.h>
#include <hip/hip_bf16.h>
#include <cmath>

#define TSIZE (1 << 19)   // hash table entries per level

typedef __bf16 bf16x8 __attribute__((ext_vector_type(8)));
typedef float  f32x4  __attribute__((ext_vector_type(4)));

struct Res16 { int r[16]; };

#define S0K 144.269504088896340f   // 100/ln2
#define SW2 0.00693147180559945f   // ln2/100

// float -> bf16 bits, round-to-nearest-even (scalar fallback path)
static __device__ __forceinline__ short f2bf(float f) {
    union { float f; unsigned u; } v; v.f = f;
    unsigned r = v.u + 0x7FFFu + ((v.u >> 16) & 1u);
    return (short)(r >> 16);
}

// packed pair -> 2x bf16 in one u32 (v_cvt_pk_bf16_f32 on gfx950)
static __device__ __forceinline__ unsigned pkbf(float a, float b) {
    union { __hip_bfloat162 h; unsigned u; } cv;
    cv.h = __float22bfloat162_rn(make_float2(a, b));
    return cv.u;
}

// base-2 softplus core (exact form, used by dormant general kernel + table build)
static __device__ __forceinline__ float spr2(float t) {
    float e = __builtin_amdgcn_exp2f(-fabsf(t));
    return fmaxf(t, 0.0f) + __builtin_amdgcn_logf(1.0f + e);
}

// table-based softplus core: max(t,0) + c(|t|), c from 1024-entry LDS table
// (t in [0,16), delta=1/64, center-sampled: abs err <= 3.9e-3 in t'-units,
//  i.e. 2.7e-5 in h-units — below bf16 quantization of h)
static __device__ __forceinline__ float spr2t(float t, const float* __restrict__ sT) {
    float u = fminf(fabsf(t) * 64.0f, 1023.0f);
    int i = (int)u;
    return fmaxf(t, 0.0f) + sT[i];
}

// swizzled LDS offset: row m, col k, row stride `stride` (shorts).
static __device__ __forceinline__ int swz(int m, int k, int stride) {
    return m * stride + ((((k >> 3) ^ (m & 7)) << 3) | (k & 7));
}

static __device__ __forceinline__ bool bit(const unsigned mk[4], int k) {
    return (mk[k >> 5] >> (k & 31)) & 1u;
}

static __device__ __forceinline__ bool fastcase(const unsigned mk[4]) {
    return (((mk[0] & ~7u) | mk[1] | mk[2] | (mk[3] & 0x01FFFFFFu)) == 0u);
}

// Pack W0 [256,121] (x 100/ln2) and W1 [256,256] into MFMA fragment order:
// ((kt*256 + n)*4 + q)*8 + j  holds  W[n][kt*32+q*8+j] (bf16).
// Block 0: live-column bitmask of W0.
// Block 1: Gc {b0',b1',W2'} (general kernel) + Wi float4{w0x',w0y',w0z',b0'}
//          + We float2{b1',W2'} (fast kernel, L1-resident const reads).
__global__ __launch_bounds__(256) void pack_weights(
    const float* __restrict__ W0, const float* __restrict__ W1,
    const float* __restrict__ b0, const float* __restrict__ b1,
    const float* __restrict__ W2,
    short* __restrict__ B0p, short* __restrict__ B1p,
    unsigned* __restrict__ mask, float* __restrict__ Gc,
    float4* __restrict__ Wi, float2* __restrict__ We) {
    int tid = threadIdx.x;
    int i = blockIdx.x * 256 + tid;              // 0..65535
    int j = i & 7, q = (i >> 3) & 3, n = (i >> 5) & 255, kt = i >> 13;
    int k = kt * 32 + q * 8 + j;
    if (i < 32768) {                             // B0p: kt 0..3 (K=128, 121 used)
        B0p[i] = f2bf(k < 121 ? S0K * W0[n * 121 + k] : 0.0f);
    }
    B1p[i] = f2bf(W1[n * 256 + k]);              // B1p: kt 0..7 (unchanged scale)

    if (blockIdx.x == 0) {
        __shared__ unsigned lm[4];
        if (tid < 4) lm[tid] = 0u;
        __syncthreads();
        unsigned acc[4] = {0u, 0u, 0u, 0u};
        for (int e = tid; e < 256 * 121; e += 256) {   // coalesced flat scan
            if (W0[e] != 0.0f) { int kc = e % 121; acc[kc >> 5] |= 1u << (kc & 31); }
        }
        #pragma unroll
        for (int wi = 0; wi < 4; ++wi) if (acc[wi]) atomicOr(&lm[wi], acc[wi]);
        __syncthreads();
        if (tid < 4) mask[tid] = lm[tid];
    }
    if (blockIdx.x == 1) {
        Gc[tid]       = S0K * b0[tid];
        Gc[256 + tid] = S0K * b1[tid];
        Gc[512 + tid] = SW2 * W2[tid];
        float4 wi;
        wi.x = S0K * W0[tid * 121 + 0];
        wi.y = S0K * W0[tid * 121 + 1];
        wi.z = S0K * W0[tid * 121 + 2];
        wi.w = S0K * b0[tid];
        Wi[tid] = wi;
        float2 we;
        we.x = S0K * b1[tid];
        we.y = SW2 * W2[tid];
        We[tid] = we;
    }
}

// FAST kernel: runs only when live W0 cols are a subset of {x,y,z}.
// Layer 0 = rank-3 affine; softplus via LDS table (transcendentals moved off
// the VALU pipe); packed bf16 converts; consts from L1-resident global.
__global__ __launch_bounds__(256, 3) void fused_fast(
    const float* __restrict__ x,
    const short* __restrict__ B1p, const unsigned* __restrict__ mask,
    const float4* __restrict__ Wi, const float2* __restrict__ We,
    const float* __restrict__ b2,
    float* __restrict__ out, int npts)
{
    unsigned mk[4];
    mk[0] = mask[0]; mk[1] = mask[1]; mk[2] = mask[2]; mk[3] = mask[3];
    if (!fastcase(mk)) return;   // general kernel owns this case

    __shared__ short sB[64 * 256];   // H0' tile [64 pts][256] bf16, swizzled (32 KB)
    __shared__ float sT[1024];       // softplus-correction table (4 KB)
    __shared__ float sX[192];
    __shared__ float sP[256];

    const int tid = threadIdx.x;
    const int blk = blockIdx.x;

    // build table + stage x (coalesced)
    #pragma unroll
    for (int i = 0; i < 4; ++i) {
        int idx = tid + i * 256;
        float t = ((float)idx + 0.5f) * (1.0f / 64.0f);
        sT[idx] = __builtin_amdgcn_logf(1.0f + __builtin_amdgcn_exp2f(-t));
    }
    if (tid < 192) {
        int xi = blk * 192 + tid;
        sX[tid] = (xi < npts * 3) ? x[xi] : 0.0f;
    }
    __syncthreads();   // (A)

    // ---- layer 0: H0'[m][n] = spr2(x.w0 + b0'), thread = (point m, seg) ----
    {
        const int m = tid & 63;          // point = lane
        const int seg = tid >> 6;        // hidden quarter (wave-uniform)
        float x0 = sX[m * 3 + 0], x1 = sX[m * 3 + 1], x2 = sX[m * 3 + 2];
        #pragma unroll 2
        for (int g8 = 0; g8 < 8; ++g8) {
            int n0 = seg * 64 + g8 * 8;
            float h[8];
            #pragma unroll
            for (int jj = 0; jj < 8; ++jj) {
                float4 wv = Wi[n0 + jj];     // L1-hit broadcast load
                float t = fmaf(x0, wv.x, fmaf(x1, wv.y, fmaf(x2, wv.z, wv.w)));
                h[jj] = spr2t(t, sT);
            }
            union { int4 i4; unsigned u[4]; } P;
            #pragma unroll
            for (int kk = 0; kk < 4; ++kk) P.u[kk] = pkbf(h[2 * kk], h[2 * kk + 1]);
            int c = n0 >> 3;
            *(int4*)&sB[m * 256 + ((c ^ (m & 7)) << 3)] = P.i4;   // ds_write_b128
        }
    }

    __syncthreads();   // (B) sB ready

    const int lane = tid & 63, w = tid >> 6;
    const int quad = lane >> 4, l15 = lane & 15;
    const int nb = w * 64;

    const f32x4 zero = {0.f, 0.f, 0.f, 0.f};
    f32x4 acc[4][4];   // [ni (hidden-1 frag)][mj (point frag)]
    #pragma unroll
    for (int ni = 0; ni < 4; ++ni)
        #pragma unroll
        for (int mj = 0; mj < 4; ++mj) acc[ni][mj] = zero;

    // GEMM1': D[n'][m] = sum_k W1[n'][k] H0'[m][k]   (K = 256)
    #pragma unroll
    for (int kt = 0; kt < 8; ++kt) {
        bf16x8 afr[4], bfr[4];
        #pragma unroll
        for (int ni = 0; ni < 4; ++ni)
            afr[ni] = *(const bf16x8*)&B1p[((kt * 256 + nb + ni * 16 + l15) * 4 + quad) * 8];
        #pragma unroll
        for (int mj = 0; mj < 4; ++mj) {
            int m = mj * 16 + l15, c = kt * 4 + quad;
            bfr[mj] = *(const bf16x8*)&sB[m * 256 + ((c ^ (m & 7)) << 3)];
        }
        #pragma unroll
        for (int ni = 0; ni < 4; ++ni)
            #pragma unroll
            for (int mj = 0; mj < 4; ++mj)
                acc[ni][mj] = __builtin_amdgcn_mfma_f32_16x16x32_bf16(afr[ni], bfr[mj], acc[ni][mj], 0, 0, 0);
    }

    // epilogue: out = sum_n' spr2(acc + b1') * W2' + b2
    #pragma unroll
    for (int mj = 0; mj < 4; ++mj) {
        float p = 0.0f;
        #pragma unroll
        for (int ni = 0; ni < 4; ++ni) {
            int n0 = nb + ni * 16 + quad * 4;
            float4 e0 = *(const float4*)&We[n0];       // (b1,w2) for n0, n0+1
            float4 e1 = *(const float4*)&We[n0 + 2];   // (b1,w2) for n0+2, n0+3
            p += spr2t(acc[ni][mj][0] + e0.x, sT) * e0.y;
            p += spr2t(acc[ni][mj][1] + e0.z, sT) * e0.w;
            p += spr2t(acc[ni][mj][2] + e1.x, sT) * e1.y;
            p += spr2t(acc[ni][mj][3] + e1.z, sT) * e1.w;
        }
        p += __shfl_xor(p, 16);
        p += __shfl_xor(p, 32);
        if (quad == 0) sP[(mj * 16 + l15) * 4 + w] = p;
    }

    __syncthreads();   // (C)

    if (tid < 64) {
        float s = sP[tid * 4 + 0] + sP[tid * 4 + 1] + sP[tid * 4 + 2] + sP[tid * 4 + 3] + b2[0];
        int pt = blk * 64 + tid;
        if (pt < npts) out[pt] = s;
    }
}

// GENERAL kernel (dormant for this data): full encode + GEMM0 + GEMM1,
// persistent 512 blocks. Early-exits when the fast case holds.
__global__ __launch_bounds__(256, 2) void fused_general(
    const float* __restrict__ x, const float* __restrict__ table,
    const float* __restrict__ Gc, const float* __restrict__ b2,
    const short* __restrict__ B0p, const short* __restrict__ B1p,
    const unsigned* __restrict__ mask,
    float* __restrict__ out, int npts, Res16 R)
{
    unsigned mk[4];
    mk[0] = mask[0]; mk[1] = mask[1]; mk[2] = mask[2]; mk[3] = mask[3];
    if (fastcase(mk)) return;    // fast kernel owns this case

    __shared__ short sA[64 * 128];
    __shared__ short sB[64 * 256];
    __shared__ float sX[192];
    __shared__ float sC[768];        // b0' | b1' | W2'
    __shared__ float sP[256];

    const int tid = threadIdx.x;
    const int lane = tid & 63, w = tid >> 6;
    const int quad = lane >> 4, l15 = lane & 15;
    const int nb = w * 64;

    bool ktl[4];
    ktl[0] = mk[0] != 0u;
    ktl[1] = mk[1] != 0u;
    ktl[2] = mk[2] != 0u;
    ktl[3] = (mk[3] & 0x01FFFFFFu) != 0u;
    const float b2r = b2[0];

    sC[tid]       = Gc[tid];
    sC[256 + tid] = Gc[256 + tid];
    sC[512 + tid] = Gc[512 + tid];
    {
        int4 z; z.x = 0; z.y = 0; z.z = 0; z.w = 0;
        int4* p = (int4*)sA;
        #pragma unroll
        for (int i = 0; i < 4; ++i) p[tid + i * 256] = z;
    }

    const int ntiles = (npts + 63) / 64;
    const f32x4 zero = {0.f, 0.f, 0.f, 0.f};

    for (int tile = blockIdx.x; tile < ntiles; tile += gridDim.x) {
        if (tid < 192) {
            int xi = tile * 192 + tid;
            sX[tid] = (xi < npts * 3) ? x[xi] : 0.0f;
        }
        __syncthreads();

        {
            const int m = tid >> 2;
            const int g = tid & 3;
            float xv[3];
            xv[0] = sX[m * 3 + 0]; xv[1] = sX[m * 3 + 1]; xv[2] = sX[m * 3 + 2];

            if (g == 0) {
                #pragma unroll
                for (int d = 0; d < 3; ++d) sA[swz(m, d, 128)] = f2bf(xv[d]);
            }
            for (int f = g; f < 9; f += 4) {
                float fs = (float)(1 << f);
                #pragma unroll
                for (int d = 0; d < 3; ++d) {
                    bool ns = bit(mk, 3 + f * 3 + d);
                    bool nc = bit(mk, 30 + f * 3 + d);
                    if (ns | nc) {
                        float v = xv[d] * fs;
                        if (ns) sA[swz(m, 3 + f * 3 + d, 128)]  = f2bf(__builtin_sinf(v));
                        if (nc) sA[swz(m, 30 + f * 3 + d, 128)] = f2bf(__builtin_cosf(v));
                    }
                }
            }
            #pragma unroll
            for (int li = 0; li < 4; ++li) {
                int i0 = R.r[li], i1 = R.r[4 + li], i2 = R.r[8 + li], i3 = R.r[12 + li];
                int res = (g == 0) ? i0 : (g == 1) ? i1 : (g == 2) ? i2 : i3;
                int lvl = g * 4 + li;
                int kb = 57 + lvl * 4;
                bool need = bit(mk, kb) | bit(mk, kb + 1) | bit(mk, kb + 2) | bit(mk, kb + 3);
                if (!need) continue;
                int rp1 = res + 1;
                bool dense = (rp1 <= 80);
                float fx[3]; int pi[3];
                #pragma unroll
                for (int d = 0; d < 3; ++d) {
                    float p  = xv[d] * (float)res;
                    float pf = floorf(p);
                    fx[d] = p - pf;
                    int qv = (int)pf;
                    pi[d] = min(max(qv, 0), res - 1);
                }
                float a0 = 0.f, a1 = 0.f, a2 = 0.f, a3 = 0.f;
                const float* tb = table + (size_t)lvl * (TSIZE * 4);
                #pragma unroll
                for (int c = 0; c < 8; ++c) {
                    int cx = pi[0] + (c & 1);
                    int cy = pi[1] + ((c >> 1) & 1);
                    int cz = pi[2] + ((c >> 2) & 1);
                    unsigned di = (unsigned)(cx + cy * rp1 + cz * rp1 * rp1);
                    unsigned hi = ((unsigned)cx ^ ((unsigned)cy * 2654435761u)
                                                ^ ((unsigned)cz * 805459861u)) & (unsigned)(TSIZE - 1);
                    unsigned idx = dense ? di : hi;
                    float4 t = *(const float4*)(tb + (size_t)idx * 4);
                    float wgt = ((c & 1) ? fx[0] : 1.0f - fx[0])
                              * ((c & 2) ? fx[1] : 1.0f - fx[1])
                              * ((c & 4) ? fx[2] : 1.0f - fx[2]);
                    a0 += wgt * t.x; a1 += wgt * t.y; a2 += wgt * t.z; a3 += wgt * t.w;
                }
                sA[swz(m, kb + 0, 128)] = f2bf(a0);
                sA[swz(m, kb + 1, 128)] = f2bf(a1);
                sA[swz(m, kb + 2, 128)] = f2bf(a2);
                sA[swz(m, kb + 3, 128)] = f2bf(a3);
            }
        }

        __syncthreads();

        f32x4 acc[4][4];
        #pragma unroll
        for (int ni = 0; ni < 4; ++ni)
            #pragma unroll
            for (int mj = 0; mj < 4; ++mj) acc[ni][mj] = zero;

        #pragma unroll
        for (int kt = 0; kt < 4; ++kt) {
            if (!ktl[kt]) continue;
            bf16x8 afr[4], bfr[4];
            #pragma unroll
            for (int ni = 0; ni < 4; ++ni)
                afr[ni] = *(const bf16x8*)&B0p[((kt * 256 + nb + ni * 16 + l15) * 4 + quad) * 8];
            #pragma unroll
            for (int mj = 0; mj < 4; ++mj) {
                int m = mj * 16 + l15, c = kt * 4 + quad;
                bfr[mj] = *(const bf16x8*)&sA[m * 128 + ((c ^ (m & 7)) << 3)];
            }
            #pragma unroll
            for (int ni = 0; ni < 4; ++ni)
                #pragma unroll
                for (int mj = 0; mj < 4; ++mj)
                    acc[ni][mj] = __builtin_amdgcn_mfma_f32_16x16x32_bf16(afr[ni], bfr[mj], acc[ni][mj], 0, 0, 0);
        }

        #pragma unroll
        for (int ni = 0; ni < 4; ++ni) {
            float4 b0v = *(const float4*)&sC[nb + ni * 16 + quad * 4];
            int c = (nb + ni * 16 + quad * 4) >> 3;
            #pragma unroll
            for (int mj = 0; mj < 4; ++mj) {
                int m = mj * 16 + l15;
                short4 h;
                h.x = f2bf(spr2(acc[ni][mj][0] + b0v.x));
                h.y = f2bf(spr2(acc[ni][mj][1] + b0v.y));
                h.z = f2bf(spr2(acc[ni][mj][2] + b0v.z));
                h.w = f2bf(spr2(acc[ni][mj][3] + b0v.w));
                *(short4*)&sB[m * 256 + (((c ^ (m & 7)) << 3) | ((quad & 1) << 2))] = h;
            }
        }

        __syncthreads();

        #pragma unroll
        for (int ni = 0; ni < 4; ++ni)
            #pragma unroll
            for (int mj = 0; mj < 4; ++mj) acc[ni][mj] = zero;

        #pragma unroll
        for (int kt = 0; kt < 8; ++kt) {
            bf16x8 afr[4], bfr[4];
            #pragma unroll
            for (int ni = 0; ni < 4; ++ni)
                afr[ni] = *(const bf16x8*)&B1p[((kt * 256 + nb + ni * 16 + l15) * 4 + quad) * 8];
            #pragma unroll
            for (int mj = 0; mj < 4; ++mj) {
                int m = mj * 16 + l15, c = kt * 4 + quad;
                bfr[mj] = *(const bf16x8*)&sB[m * 256 + ((c ^ (m & 7)) << 3)];
            }
            #pragma unroll
            for (int ni = 0; ni < 4; ++ni)
                #pragma unroll
                for (int mj = 0; mj < 4; ++mj)
                    acc[ni][mj] = __builtin_amdgcn_mfma_f32_16x16x32_bf16(afr[ni], bfr[mj], acc[ni][mj], 0, 0, 0);
        }

        #pragma unroll
        for (int mj = 0; mj < 4; ++mj) {
            float p = 0.0f;
            #pragma unroll
            for (int ni = 0; ni < 4; ++ni) {
                float4 b1v = *(const float4*)&sC[256 + nb + ni * 16 + quad * 4];
                float4 w2v = *(const float4*)&sC[512 + nb + ni * 16 + quad * 4];
                p += spr2(acc[ni][mj][0] + b1v.x) * w2v.x;
                p += spr2(acc[ni][mj][1] + b1v.y) * w2v.y;
                p += spr2(acc[ni][mj][2] + b1v.z) * w2v.z;
                p += spr2(acc[ni][mj][3] + b1v.w) * w2v.w;
            }
            p += __shfl_xor(p, 16);
            p += __shfl_xor(p, 32);
            if (quad == 0) sP[(mj * 16 + l15) * 4 + w] = p;
        }

        __syncthreads();

        if (tid < 64) {
            float s = sP[tid * 4 + 0] + sP[tid * 4 + 1] + sP[tid * 4 + 2] + sP[tid * 4 + 3] + b2r;
            int pt = tile * 64 + tid;
            if (pt < npts) out[pt] = s;
        }
        __syncthreads();
    }
}

extern "C" void kernel_launch(void* const* d_in, const int* in_sizes, int n_in,
                              void* d_out, int out_size, void* d_ws, size_t ws_size,
                              hipStream_t stream) {
    const float* x     = (const float*)d_in[0];
    const float* table = (const float*)d_in[1];
    const float* W0    = (const float*)d_in[2];
    const float* b0    = (const float*)d_in[3];
    const float* W1    = (const float*)d_in[4];
    const float* b1    = (const float*)d_in[5];
    const float* W2    = (const float*)d_in[6];
    const float* b2    = (const float*)d_in[7];
    float* out = (float*)d_out;
    int npts = in_sizes[0] / 3;

    // ws: B0p 32768 sh | B1p 65536 sh | mask 8 u32 | Gc 768 f32 | Wi 256 f4 | We 256 f2
    short* B0p = (short*)d_ws;
    short* B1p = B0p + 32768;
    unsigned* mask = (unsigned*)(B1p + 65536);
    float* Gc = (float*)(mask + 8);
    float4* Wi = (float4*)(Gc + 768);
    float2* We = (float2*)(Wi + 256);

    // RES table: must match Python bit-for-bit -> identical libm expression.
    Res16 R;
    double s = ::pow(2.0, ::log2(2048.0 / 16.0) / 15.0);
    for (int l = 0; l < 16; ++l) R.r[l] = (int)::ceil(16.0 * ::pow(s, (double)l));

    hipLaunchKernelGGL(pack_weights, dim3(256), dim3(256), 0, stream,
                       W0, W1, b0, b1, W2, B0p, B1p, mask, Gc, Wi, We);
    hipLaunchKernelGGL(fused_general, dim3(512), dim3(256), 0, stream,
                       x, table, Gc, b2, B0p, B1p, mask, out, npts, R);
    int nblk = (npts + 63) / 64;
    hipLaunchKernelGGL(fused_fast, dim3(nblk), dim3(256), 0, stream,
                       x, B1p, mask, Wi, We, b2, out, npts);
}